// Round 10
// baseline (272.590 us; speedup 1.0000x reference)
//
#include <hip/hip_runtime.h>

// DynamicDilationUnfold: B=4, C=64, H=W=128, G=4, Cg=16, K=3, stride=1, pad=1.
// out[b][((g*Cg+cg)*K+kh)*K+kw][ho*Wo+wo], fp32.
//
// R14: SACRIFICIAL DIAGNOSTIC. Six rounds of store-side theories are all
// flat/worse (geometry, policy, count, run length, occupancy) and the kernel
// never surfaces in top-5 (always just under the ~90us poison fills), so we
// have zero direct counter evidence. This round measures the split
// empirically through the graded time itself:
//   launch ddu_kernel<0> (NO-STORE: gather+VALU+staging kept live via
//   asm keep-alive, per guide rule #17)  x4
//   then ddu_kernel<1> (EXACT R8)        x1   -> correct final output
// A = (graded - fill - 75*s)/4. Predictions (committed):
//   store-side dominant: A ~ 25-32  -> graded ~275
//   gather-side dominant: A ~ 55-65 -> graded ~400
//   smeared/stall-bound:  A ~ 40-47 -> graded ~330-355
// Best kernel remains R8 (164.3 graded); revert/act next round.

constexpr int B  = 4;
constexpr int C  = 64;
constexpr int H  = 128;
constexpr int W  = 128;
constexpr int G  = 4;
constexpr int Cg = C / G;            // 16
constexpr int K  = 3;
constexpr int KK = K * K;
constexpr int Ho = 128;
constexpr int Wo = 128;
constexpr int HW = H * W;
constexpr int HoWo = Ho * Wo;

constexpr int TILE_H = 16;           // rows per block, full 128-col width
constexpr int CPB    = 4;            // channels per block
constexpr int REG_H  = 22;           // region rows: image ro0-1 .. ro0+20
constexpr int REG_W  = 134;          // region cols: image -1 .. 132
constexpr int LDS_STRIDE = 135;      // odd stride -> bank-decorrelated
constexpr int CH_STRIDE  = REG_H * LDS_STRIDE;   // 2970 dwords per channel
constexpr int NSTAGE     = CPB * CH_STRIDE;      // 11880 dwords = 47,520 B
constexpr int NTHREADS   = 1024;

template <int STORES>   // 0 = no-store ablation (keep-alive), 1 = full (exact R8)
__global__ __launch_bounds__(NTHREADS, 8) void ddu_kernel(
    const float* __restrict__ x,      // (B, C, H, W)
    const float* __restrict__ dmap,   // (B, G, H, W)
    float* __restrict__ out)          // (B, C*K*K, Ho*Wo)
{
    __shared__ float lds[NSTAGE];                // 47,520 B -> 2 blocks/CU

    const int tid = threadIdx.x;
    const int bid = blockIdx.x;                  // 512 = b(4) g(4) chunk(4) rt(8)
    const int rt    = bid & 7;
    const int chunk = (bid >> 3) & 3;
    const int g     = (bid >> 5) & 3;
    const int b     = bid >> 7;

    const int ro0 = rt * TILE_H;
    const int cgb = chunk * CPB;

    const float* __restrict__ xg = x + (size_t)(b * C + g * Cg + cgb) * HW;

    // ---- stage: channel-planar scalar LDS, coalesced dword loads, zero halo ----
#pragma unroll
    for (int it = 0; it < (NSTAGE + NTHREADS - 1) / NTHREADS; ++it) {
        const int p = it * NTHREADS + tid;
        if (p < NSTAGE) {
            const int ch  = p / CH_STRIDE;
            const int rem = p - ch * CH_STRIDE;
            const int rr  = rem / LDS_STRIDE;
            const int cc  = rem - rr * LDS_STRIDE;
            const int ir  = ro0 - 1 + rr;
            const int ic  = cc - 1;
            float v = 0.f;
            if ((unsigned)ir < (unsigned)H && (unsigned)ic < (unsigned)W && cc < REG_W)
                v = xg[(size_t)ch * HW + ir * W + ic];
            lds[p] = v;                          // zero halo == validity mask
        }
    }
    __syncthreads();

    // ---- compute: each thread owns 2 adjacent wo; wave = one full row ----
    const int wi2 = tid & 63;                    // wo-pair 0..63 (full 128 cols)
    const int hi  = tid >> 6;                    // 0..15
    const int ho  = ro0 + hi;
    const int wo  = wi2 * 2;

    const float2 dv = *(const float2*)&dmap[(size_t)(b * G + g) * HoWo + ho * Wo + wo];
    const float d0 = dv.x;
    const float d1 = dv.y;

    float* __restrict__ outb = out
        + (size_t)((b * C + g * Cg + cgb) * KK) * HoWo
        + (size_t)(ho * Wo + wo);

    const float col0 = (float)wo;                // region col of subpixel 0
    const float col1 = (float)(wo + 1);
    const float rowf = (float)hi;                // region row coordinate base

#pragma unroll
    for (int kh = 0; kh < K; ++kh) {
        const float ph0 = rowf + (float)kh * d0;
        const float ph1 = rowf + (float)kh * d1;
        const int   r0  = (int)ph0;              // <= 20
        const int   r1  = (int)ph1;
        const float lh0 = ph0 - (float)r0;
        const float lh1 = ph1 - (float)r1;
        const float mh0 = 1.f - lh0;
        const float mh1 = 1.f - lh1;

#pragma unroll
        for (int kw = 0; kw < K; ++kw) {
            const float pw0 = col0 + (float)kw * d0;
            const float pw1 = col1 + (float)kw * d1;
            const int   c0  = (int)pw0;          // <= 132
            const int   c1  = (int)pw1;
            const float lw0 = pw0 - (float)c0;
            const float lw1 = pw1 - (float)c1;

            const float a00 = mh0 * (1.f - lw0);
            const float a01 = mh0 * lw0;
            const float a10 = lh0 * (1.f - lw0);
            const float a11 = lh0 * lw0;

            const float b00 = mh1 * (1.f - lw1);
            const float b01 = mh1 * lw1;
            const float b10 = lh1 * (1.f - lw1);
            const float b11 = lh1 * lw1;

            const int base0 = r0 * LDS_STRIDE + c0;
            const int base1 = r1 * LDS_STRIDE + c1;

            float* __restrict__ o = outb + (size_t)(kh * K + kw) * HoWo;

#pragma unroll
            for (int ch = 0; ch < CPB; ++ch) {
                const float* __restrict__ l  = lds + ch * CH_STRIDE;
                const float* __restrict__ l0 = l + base0;
                const float* __restrict__ l1 = l + base1;
                float2 v;
                v.x = a00 * l0[0] + a01 * l0[1]
                    + a10 * l0[LDS_STRIDE] + a11 * l0[LDS_STRIDE + 1];
                v.y = b00 * l1[0] + b01 * l1[1]
                    + b10 * l1[LDS_STRIDE] + b11 * l1[LDS_STRIDE + 1];
                if constexpr (STORES) {
                    *(float2*)(o + (size_t)ch * (KK * HoWo)) = v;
                } else {
                    // keep gather + FMA chain live without any VMEM write
                    asm volatile("" :: "v"(v.x), "v"(v.y));
                }
            }
        }
    }
}

extern "C" void kernel_launch(void* const* d_in, const int* in_sizes, int n_in,
                              void* d_out, int out_size, void* d_ws, size_t ws_size,
                              hipStream_t stream) {
    const float* x    = (const float*)d_in[0];
    const float* dmap = (const float*)d_in[1];
    float* out = (float*)d_out;

    const int grid = B * G * (Cg / CPB) * (Ho / TILE_H);   // 512 = 2 blocks/CU

    // 4x no-store ablation (amplified signal), then 1x exact-R8 correct pass
    ddu_kernel<0><<<grid, NTHREADS, 0, stream>>>(x, dmap, out);
    ddu_kernel<0><<<grid, NTHREADS, 0, stream>>>(x, dmap, out);
    ddu_kernel<0><<<grid, NTHREADS, 0, stream>>>(x, dmap, out);
    ddu_kernel<0><<<grid, NTHREADS, 0, stream>>>(x, dmap, out);
    ddu_kernel<1><<<grid, NTHREADS, 0, stream>>>(x, dmap, out);
}